// Round 13
// baseline (130.432 us; speedup 1.0000x reference)
//
#include <hip/hip_runtime.h>
#include <hip/hip_bf16.h>
#include <stdint.h>

typedef __attribute__((ext_vector_type(8))) short short8;
typedef __attribute__((ext_vector_type(4))) float f32x4;

#define NROWS  8192
#define DDIM   256
#define HHEADS 4
#define KTOT   1024
#define BM     256
#define BN     128
#define BK     32
#define NT     (KTOT / BK)        // 32 K-tiles
#define NRB    (NROWS / BM)       // 32 row-blocks
#define NJOBS  (NRB * NRB + NRB)  // sum(2i+2) = 1056 = 8*132
#define BUFE   12288              // elems per K-tile buf: A 8192 + B 4096 (24 KB)

#define SBAR()  __builtin_amdgcn_s_barrier()
#define LGKM0() do { asm volatile("s_waitcnt lgkmcnt(0)" ::: "memory"); \
                     __builtin_amdgcn_sched_barrier(0); } while (0)
#define VMCNT(n) do { asm volatile("s_waitcnt vmcnt(" #n ")" ::: "memory"); \
                      __builtin_amdgcn_sched_barrier(0); } while (0)

__device__ __forceinline__ unsigned short f2bf(float f) {
  union { float f; uint32_t u; } v;
  v.f = f;
  uint32_t u = v.u;
  uint32_t r = (u + 0x7fffu + ((u >> 16) & 1u)) >> 16;
  return (unsigned short)r;
}

// --------------------------------------------------------------------------
// Kernel 1: Y[n, h*256+d] = bf16-normalized per-head scaled rows
// --------------------------------------------------------------------------
__global__ __launch_bounds__(256) void prep_y(const float* __restrict__ x,
                                              const float* __restrict__ av,
                                              unsigned short* __restrict__ Y) {
  __shared__ float a_sh[HHEADS][DDIM];
  __shared__ float red[4][HHEADS];

  const int t = threadIdx.x;
  #pragma unroll
  for (int h = 0; h < HHEADS; ++h) a_sh[h][t] = av[h * DDIM + t];
  __syncthreads();

  const int n = blockIdx.x;
  const float xd = x[(size_t)n * DDIM + t];

  float p[HHEADS], s[HHEADS];
  #pragma unroll
  for (int h = 0; h < HHEADS; ++h) { p[h] = a_sh[h][t] * xd; s[h] = p[h] * p[h]; }

  #pragma unroll
  for (int off = 32; off > 0; off >>= 1) {
    #pragma unroll
    for (int h = 0; h < HHEADS; ++h) s[h] += __shfl_xor(s[h], off, 64);
  }

  const int wave = t >> 6, lane = t & 63;
  if (lane == 0) {
    #pragma unroll
    for (int h = 0; h < HHEADS; ++h) red[wave][h] = s[h];
  }
  __syncthreads();

  #pragma unroll
  for (int h = 0; h < HHEADS; ++h) {
    const float sum = red[0][h] + red[1][h] + red[2][h] + red[3][h];
    const float rn = rsqrtf(fmaxf(sum, 1e-12f));
    Y[(size_t)n * KTOT + h * DDIM + t] = f2bf(p[h] * rn);
  }
}

// --------------------------------------------------------------------------
// stage one 24 KB K-tile (A 256x32 + B 128x32 bf16): 3 global_load_lds(16B)
// per thread.  Linear LDS dest; add-rotate swizzle slot'=(slot+(row>>1))&3
// applied on the GLOBAL source (rule #21).
// --------------------------------------------------------------------------
__device__ __forceinline__ void stage_tile(const unsigned short* __restrict__ Y,
                                           unsigned short* buf,
                                           int rowA0, int rowB0, int k0, int tid) {
  #pragma unroll
  for (int i = 0; i < 2; ++i) {                    // A region: 1024 slots
    const int s   = i * 512 + tid;
    const int r   = s >> 2;
    const int gsl = ((s & 3) + 4 - ((r >> 1) & 3)) & 3;
    const unsigned short* gsrc = Y + (size_t)(rowA0 + r) * KTOT + k0 + gsl * 8;
    __builtin_amdgcn_global_load_lds(
        (const __attribute__((address_space(1))) void*)gsrc,
        (__attribute__((address_space(3))) void*)(buf + s * 8), 16, 0, 0);
  }
  {                                                // B region: 512 slots
    const int s   = tid;
    const int r   = s >> 2;
    const int gsl = ((s & 3) + 4 - ((r >> 1) & 3)) & 3;
    const unsigned short* gsrc = Y + (size_t)(rowB0 + r) * KTOT + k0 + gsl * 8;
    __builtin_amdgcn_global_load_lds(
        (const __attribute__((address_space(1))) void*)gsrc,
        (__attribute__((address_space(3))) void*)(buf + 8192 + s * 8), 16, 0, 0);
  }
}

// --------------------------------------------------------------------------
// Kernel 2: C = Y*Y^T / 4 on 256x128 tiles, tri-buffered BK=32 K-loop,
// 2 blocks/CU co-resident (LDS 72 KB, <=128 VGPR via __launch_bounds__).
// Job (i,j): row-block i (256 rows), col-block j (128 cols), j < 2i+2;
// straddlers (j >= 2i) skip the mirror.
//
// EPILOGUE CHANGE (round 13): BOTH write paths go through LDS so every HBM
// store instruction is full-line contiguous (f32x4, 512B per 32 lanes).
// Evidence: r1 showed FETCH == 2x WRITE (write-allocate RMW on the partial-
// line straight stores); r10 showed the LDS-staged mirror path avoids it
// (FETCH 104MB vs WRITE 270MB).  Direct per-fragment straight stores (64B
// chunks spread over 4 rows) were fetching C from HBM before writing it.
// --------------------------------------------------------------------------
__global__ __launch_bounds__(512, 4) void gemm_yyt(const unsigned short* __restrict__ Y,
                                                   float* __restrict__ C) {
  __shared__ __attribute__((aligned(16))) unsigned short lds[3 * BUFE];  // 73.7 KB

  // bijective XCD swizzle: 1056 = 8 * 132
  const int orig = blockIdx.x;
  const int wg   = (orig & 7) * (NJOBS / 8) + (orig >> 3);

  // decode: jobs before row-block i = i*i + i ; j in [0, 2i+2)
  int i = (int)((sqrtf(4.0f * (float)wg + 1.0f) - 1.0f) * 0.5f);
  while ((i + 1) * (i + 1) + (i + 1) <= wg) ++i;
  while (i * i + i > wg) --i;
  const int j = wg - i * i - i;

  const int rowA0 = i * BM;          // C row block (256)
  const int rowB0 = j * BN;          // C col block (128)
  const bool mirror = (j < 2 * i);

  const int tid  = threadIdx.x;
  const int lane = tid & 63;
  const int wv   = tid >> 6;
  const int wr   = wv >> 1;          // 0..3 (M)
  const int wn   = wv & 1;           // 0..1 (N)
  const int l15  = lane & 15;
  const int lh   = lane >> 4;        // 0..3

  f32x4 acc[4][4];
  #pragma unroll
  for (int m = 0; m < 4; ++m)
    #pragma unroll
    for (int n = 0; n < 4; ++n) acc[m][n] = (f32x4){0.f, 0.f, 0.f, 0.f};

  // prologue: stage K-tiles 0 and 1
  stage_tile(Y, lds + 0,    rowA0, rowB0, 0,  tid);
  stage_tile(Y, lds + BUFE, rowA0, rowB0, BK, tid);
  VMCNT(3);    // tile 0 landed; tile 1's 3 loads may fly
  SBAR();
  __builtin_amdgcn_sched_barrier(0);

  int cur = 0;
  int nx2 = 2 * BUFE;
  short8 af[4], bf[4];

  for (int T = 0; T < NT; ++T) {
    if (T + 2 < NT) stage_tile(Y, lds + nx2, rowA0, rowB0, (T + 2) * BK, tid);

    #pragma unroll
    for (int m = 0; m < 4; ++m) {
      const int r_ = wr * 64 + m * 16 + l15;
      const int sl = (lh + ((r_ >> 1) & 3)) & 3;
      af[m] = *(const short8*)(lds + cur + r_ * 32 + sl * 8);
    }
    #pragma unroll
    for (int n = 0; n < 4; ++n) {
      const int r_ = wn * 64 + n * 16 + l15;
      const int sl = (lh + ((r_ >> 1) & 3)) & 3;
      bf[n] = *(const short8*)(lds + cur + 8192 + r_ * 32 + sl * 8);
    }
    __builtin_amdgcn_sched_barrier(0);
    LGKM0();

    __builtin_amdgcn_s_setprio(1);
    #pragma unroll
    for (int m = 0; m < 4; ++m)
      #pragma unroll
      for (int n = 0; n < 4; ++n)
        acc[m][n] = __builtin_amdgcn_mfma_f32_16x16x32_bf16(
            af[m], bf[n], acc[m][n], 0, 0, 0);
    __builtin_amdgcn_s_setprio(0);
    __builtin_amdgcn_sched_barrier(0);

    if (T < NT - 2)       { VMCNT(3); }   // T+1 landed; T+2 in flight
    else if (T == NT - 2) { VMCNT(0); }   // last prefetch (T+1) landed
    SBAR();

    cur += BUFE; if (cur == 3 * BUFE) cur = 0;
    nx2 += BUFE; if (nx2 == 3 * BUFE) nx2 = 0;
  }

  // ---- PASS 1: straight write via LDS (full-line f32x4 stores) ----
  // slice s = rows [s*64, s*64+64) of the tile, owned by waves with wr==s.
  {
    float (*st)[132] = (float(*)[132])lds;   // 64 x 132 f32 = 33.8 KB
    #pragma unroll
    for (int s = 0; s < 4; ++s) {
      if (s > 0) SBAR();                 // previous slice readers done
      if (wr == s) {
        #pragma unroll
        for (int m = 0; m < 4; ++m)
          #pragma unroll
          for (int n = 0; n < 4; ++n) {
            const int cl  = wn * 64 + n * 16 + l15;     // 0..127
            const int rl0 = m * 16 + lh * 4;            // 0..60
            #pragma unroll
            for (int r = 0; r < 4; ++r)
              st[rl0 + r][cl] = acc[m][n][r];
          }
        LGKM0();                          // my ds_writes visible
      }
      SBAR();
      #pragma unroll
      for (int q = 0; q < 4; ++q) {
        const int idx = q * 512 + tid;    // 0..2047 over 64x32 f32x4
        const int ii  = idx >> 5;         // 0..63
        const int jj  = (idx & 31) * 4;   // 0..124
        f32x4 v = *(const f32x4*)&st[ii][jj];
        v *= 0.25f;
        *(f32x4*)(C + (size_t)(rowA0 + s * 64 + ii) * NROWS + rowB0 + jj) = v;
      }
    }
  }

  // ---- PASS 2: mirror write via LDS transpose (off-diagonal tiles) ----
  if (mirror) {
    float (*tr)[260] = (float(*)[260])lds;   // 32 x 260 f32 = 33.3 KB
    #pragma unroll
    for (int s = 0; s < 4; ++s) {            // col slices of 32
      SBAR();                                // pass-1 / previous slice done
      if (wn == (s >> 1)) {
        const int ns = 2 * (s & 1);
        #pragma unroll
        for (int nn = 0; nn < 2; ++nn)
          #pragma unroll
          for (int m = 0; m < 4; ++m) {
            const int cl  = nn * 16 + l15;                 // 0..31
            const int rl0 = wr * 64 + m * 16 + lh * 4;     // 0..252, %4==0
            *(f32x4*)&tr[cl][rl0] = acc[m][ns + nn];
          }
        LGKM0();                             // my ds_writes visible
      }
      SBAR();
      #pragma unroll
      for (int q = 0; q < 4; ++q) {
        const int idx = q * 512 + tid;       // 0..2047
        const int ii  = idx >> 6;            // 0..31
        const int jj  = (idx & 63) * 4;      // 0..252
        f32x4 v = *(const f32x4*)&tr[ii][jj];
        v *= 0.25f;
        *(f32x4*)(C + (size_t)(rowB0 + s * 32 + ii) * NROWS + rowA0 + jj) = v;
      }
    }
  }
}

// --------------------------------------------------------------------------
extern "C" void kernel_launch(void* const* d_in, const int* in_sizes, int n_in,
                              void* d_out, int out_size, void* d_ws, size_t ws_size,
                              hipStream_t stream) {
  (void)in_sizes; (void)n_in; (void)out_size; (void)ws_size;
  const float* x  = (const float*)d_in[0];   // [8192, 256] f32
  const float* av = (const float*)d_in[1];   // [4, 256] f32
  float* C = (float*)d_out;                  // [8192, 8192] f32
  unsigned short* Y = (unsigned short*)d_ws; // [8192, 1024] bf16 scratch (16 MiB)

  prep_y<<<NROWS, 256, 0, stream>>>(x, av, Y);
  gemm_yyt<<<NJOBS, 512, 0, stream>>>(Y, C);
}